// Round 1
// baseline (184.214 us; speedup 1.0000x reference)
//
#include <hip/hip_runtime.h>

// Problem constants (from reference):
//   x: (B=16, N_CH=1024, T=2048) fp32
//   W: (M=128, C=8) fp32
//   out0: Ax (16, 128, 2048) fp32   = 4,194,304 elems
//   out1: A_full (128, 1024) fp32   =   131,072 elems
#define B_SZ   16
#define N_CH   1024
#define T_SZ   2048
#define C_BLK  8
#define M_OUT  128

#define T4        (T_SZ / 4)            // 512 float4 per (b,m) row
#define AX_BLOCKS (B_SZ * M_OUT)        // one block per (b,m) row = 2048
#define AF_VEC4   ((M_OUT * N_CH) / 4)  // 32768 float4 for A_full

// Native clang vector type — required by __builtin_nontemporal_load/store
// (HIP_vector_type float4 is a struct and is rejected).
typedef float vfloat4 __attribute__((ext_vector_type(4)));

// Round-6 config:
//  - nt loads/stores kept (round-4 showed removing nt regresses 184->192: the
//    512 MiB d_ws poison sweeps L3 before this kernel, so x always misses and
//    allocate-on-read would force dirty-poison writebacks).
//  - NEW: A_full folded into the 2048 Ax blocks (grid == 2048 == exactly
//    8 blocks/CU * 256 CUs -> one balanced occupancy generation, no 128-block
//    straggler tail that previously ran as a serialized second dispatch wave).
//    Each block's lanes 0..15 write its 16-float4 slice of A_full, issued
//    under the x-load shadow.
//  - NEW: all 16 x nt-loads issued before any FMA (explicit unrolled register
//    array, static indices only) to pin max memory-level parallelism.
//
// Ax[b,m,t] = sum_c x[b, m*8+c, t] * W[m,c]
// A_full[r, col] = (col>>3 == r) ? W[r, col&7] : 0
__global__ __launch_bounds__(256)
void fused_kernel(const float* __restrict__ x,
                  const float* __restrict__ W,
                  float* __restrict__ ax_out,
                  float* __restrict__ afull_out) {
    const int row = blockIdx.x;                   // b*M + m in [0, 2048)
    const int m   = row & (M_OUT - 1);
    const int t4  = threadIdx.x;                  // [0,256); second elem at +256

    // base channel: b*N_CH + m*C_BLK == row*C_BLK  (N_CH = M*C)
    const vfloat4* xp = reinterpret_cast<const vfloat4*>(x)
                      + (size_t)row * C_BLK * T4 + t4;

    // ---- issue all 16 nt loads first (max MLP per wave) ----
    vfloat4 xv[2 * C_BLK];
#pragma unroll
    for (int c = 0; c < C_BLK; ++c) {
        xv[2 * c]     = __builtin_nontemporal_load(xp + c * T4);
        xv[2 * c + 1] = __builtin_nontemporal_load(xp + c * T4 + 256);
    }

    // ---- A_full slice for this block: 16 float4, lanes 0..15 ----
    // Covers i4 = row*16 + [0,16) -> [0, 32768) exactly once across the grid.
    if (threadIdx.x < 16) {
        const int i4   = row * 16 + threadIdx.x;
        const int r    = i4 >> 8;            // A_full row (256 float4 per row)
        const int col4 = i4 & 255;           // float4 index within row
        const int blk  = col4 >> 1;          // 8-col block this float4 lies in
        vfloat4 v = (vfloat4)(0.f);
        if (blk == r) {
            const vfloat4* wrow = reinterpret_cast<const vfloat4*>(W + r * C_BLK);
            v = wrow[col4 & 1];              // first or second half of W[r,:]
        }
        __builtin_nontemporal_store(v, reinterpret_cast<vfloat4*>(afull_out) + i4);
    }

    // ---- drain: FMA accumulate (W reads are wave-uniform -> SMEM path) ----
    vfloat4 acc0 = (vfloat4)(0.f);
    vfloat4 acc1 = (vfloat4)(0.f);
#pragma unroll
    for (int c = 0; c < C_BLK; ++c) {
        const float w = W[m * C_BLK + c];
        acc0 += w * xv[2 * c];
        acc1 += w * xv[2 * c + 1];
    }

    vfloat4* op = reinterpret_cast<vfloat4*>(ax_out) + (size_t)row * T4 + t4;
    __builtin_nontemporal_store(acc0, op);
    __builtin_nontemporal_store(acc1, op + 256);
}

extern "C" void kernel_launch(void* const* d_in, const int* in_sizes, int n_in,
                              void* d_out, int out_size, void* d_ws, size_t ws_size,
                              hipStream_t stream) {
    const float* x = (const float*)d_in[0];
    const float* W = (const float*)d_in[1];
    float* out = (float*)d_out;

    float* ax_out    = out;                               // 4,194,304 floats
    float* afull_out = out + (size_t)B_SZ * M_OUT * T_SZ; // next 131,072

    fused_kernel<<<AX_BLOCKS, 256, 0, stream>>>(x, W, ax_out, afull_out);
}